// Round 4
// baseline (897.802 us; speedup 1.0000x reference)
//
#include <hip/hip_runtime.h>

#define V_ 10000
#define D_ 256
#define T_ 128
#define B_ 8
#define MS_ 4
#define S_ 5
#define EOS_ 4

typedef unsigned short b16_t;
typedef __attribute__((ext_vector_type(8))) short s16x8;
typedef __attribute__((ext_vector_type(8))) unsigned short u16x8;
typedef __attribute__((ext_vector_type(4))) float f32x4;
typedef __attribute__((ext_vector_type(2))) _Float16 h16x2;

__device__ inline b16_t f2bf(float f) {
  union { float f; unsigned u; } v; v.f = f;
  unsigned r = v.u + 0x7FFFu + ((v.u >> 16) & 1u);
  return (b16_t)(r >> 16);
}
__device__ inline float bf2f(b16_t h) {
  union { unsigned u; float f; } v; v.u = ((unsigned)h) << 16; return v.f;
}
__device__ inline float sigm_(float x) { return 1.0f / (1.0f + __expf(-x)); }
__device__ inline float tanh_(float x) { return 2.0f / (1.0f + __expf(-2.0f * x)) - 1.0f; }
__device__ inline h16x2 bch(unsigned u) { return __builtin_bit_cast(h16x2, u); }
__device__ inline unsigned pkh(float a, float b) {
  h16x2 v; v.x = (_Float16)a; v.y = (_Float16)b;
  return __builtin_bit_cast(unsigned, v);
}

#if __has_builtin(__builtin_amdgcn_fdot2)
#define FDOT2(a, b, c) __builtin_amdgcn_fdot2((a), (b), (c), false)
#else
#define FDOT2(a, b, c) ((c) + (float)(a).x * (float)(b).x + (float)(a).y * (float)(b).y)
#endif

// ---------------- prep: weight casts + seq + seg(s>=1) ----------------
__device__ inline void cvt4(const float* __restrict__ s, b16_t* __restrict__ d) {
  float4 v = *(const float4*)s;
  ushort4 o = { f2bf(v.x), f2bf(v.y), f2bf(v.z), f2bf(v.w) };
  *(ushort4*)d = o;
}

__global__ void k_prep(const float* __restrict__ emb, const float* __restrict__ cWi,
                       const float* __restrict__ y0W, const float* __restrict__ hlW,
                       const float* __restrict__ l0Wi, const float* __restrict__ l0Wh,
                       const float* __restrict__ l1Wi, const float* __restrict__ l1Wh,
                       const float* __restrict__ cWh, const int* __restrict__ x_ids,
                       const float* __restrict__ y_st,
                       b16_t* __restrict__ emb_bf, b16_t* __restrict__ cWi_bf,
                       b16_t* __restrict__ y0W_bf, b16_t* __restrict__ hlW_bf,
                       b16_t* __restrict__ l0Wi_bf, b16_t* __restrict__ l0Wh_bf,
                       b16_t* __restrict__ Wcat_bf, unsigned* __restrict__ Whf,
                       b16_t* __restrict__ seq_bf, b16_t* __restrict__ seg_bf) {
  for (long i = (long)blockIdx.x * blockDim.x + threadIdx.x; i < 1410048L;
       i += (long)gridDim.x * blockDim.x) {
    if (i < 640000L) { cvt4(emb + i * 4, emb_bf + i * 4); }
    else if (i < 705536L) { long j = i - 640000L; cvt4(cWi + j * 4, cWi_bf + j * 4); }
    else if (i < 721920L) { long j = i - 705536L; cvt4(y0W + j * 4, y0W_bf + j * 4); }
    else if (i < 754688L) { long j = i - 721920L; cvt4(hlW + j * 4, hlW_bf + j * 4); }
    else if (i < 820224L) { long j = i - 754688L; cvt4(l0Wi + j * 4, l0Wi_bf + j * 4); }
    else if (i < 885760L) { long j = i - 820224L; cvt4(l0Wh + j * 4, l0Wh_bf + j * 4); }
    else if (i < 1016832L) {
      long j = (i - 885760L) * 4;
      long n = j >> 9; int k = (int)(j & 511);
      const float* src = (k < 256) ? (l1Wi + n * 256 + k) : (l1Wh + n * 256 + (k - 256));
      cvt4(src, Wcat_bf + j);
    } else if (i < 1082368L) {
      long j = i - 1016832L;
      float4 v = *(const float4*)(cWh + j * 4);
      Whf[2 * j] = pkh(v.x, v.y);
      Whf[2 * j + 1] = pkh(v.z, v.w);
    } else if (i < 1147904L) {
      long j = i - 1082368L;                    // seq_bf: [1024][256]
      int m = (int)(j >> 6), c = (int)(j & 63) * 4;
      int t = m >> 3, b = m & 7;
      const float* src = (t == 0) ? (y_st + c)
                                  : (emb + (size_t)x_ids[b * (T_ + 2) + t] * D_ + c);
      cvt4(src, seq_bf + (size_t)m * D_ + c);
    } else {
      long j = i - 1147904L;                    // seg rows s>=1: 4096 rows x 64 chunks
      int r = (int)(j >> 6), c = (int)(j & 63) * 4;
      int p = r >> 2, s = 1 + (r & 3);
      int t = p >> 3, b = p & 7;
      int tt = t + s - 1;
      int ps = r + (r >> 2) + 1;                // = p*5 + s
      if (tt < T_) {
        int tok = x_ids[b * (T_ + 2) + tt + 1];
        cvt4(emb + (size_t)tok * D_ + c, seg_bf + (size_t)ps * 256 + c);
      } else {
        ushort4 z = {0, 0, 0, 0};
        *(ushort4*)(seg_bf + (size_t)ps * 256 + c) = z;
      }
    }
  }
}

// ------- generic bf16 MFMA GEMM (K=256): C[m][n] = A[m*lda..] @ Bw[n][256]^T -------
__global__ __launch_bounds__(256) void k_gemm(const b16_t* __restrict__ A, int lda,
                                              const b16_t* __restrict__ Bw,
                                              const float* __restrict__ bias,
                                              float* __restrict__ C, int ldc,
                                              int act, int obf) {
  __shared__ b16_t As[64][264];
  __shared__ b16_t Bs[64][264];
  int tid = threadIdx.x;
  int rowBase = blockIdx.x * 64, colBase = blockIdx.y * 64;
  for (int i = tid; i < 64 * 32; i += 256) {
    int r = i >> 5, c = (i & 31) * 8;
    *(u16x8*)&As[r][c] = *(const u16x8*)(A + (size_t)(rowBase + r) * lda + c);
    *(u16x8*)&Bs[r][c] = *(const u16x8*)(Bw + (size_t)(colBase + r) * 256 + c);
  }
  __syncthreads();
  int w = tid >> 6, l = tid & 63, lr = l & 15, kg = l >> 4;
  f32x4 acc[4] = {{0.f,0.f,0.f,0.f},{0.f,0.f,0.f,0.f},{0.f,0.f,0.f,0.f},{0.f,0.f,0.f,0.f}};
  for (int kk = 0; kk < 8; ++kk) {
    s16x8 a = *(const s16x8*)&As[w * 16 + lr][kk * 32 + kg * 8];
#pragma unroll
    for (int f = 0; f < 4; ++f) {
      s16x8 b = *(const s16x8*)&Bs[f * 16 + lr][kk * 32 + kg * 8];
      acc[f] = __builtin_amdgcn_mfma_f32_16x16x32_bf16(a, b, acc[f], 0, 0, 0);
    }
  }
#pragma unroll
  for (int f = 0; f < 4; ++f) {
#pragma unroll
    for (int r = 0; r < 4; ++r) {
      int m = rowBase + w * 16 + kg * 4 + r;
      int n = colBase + f * 16 + lr;
      float v = acc[f][r];
      if (bias) v += bias[n];
      if (act == 1) v = tanh_(v);
      size_t idx = (size_t)m * ldc + n;
      if (obf) ((b16_t*)C)[idx] = f2bf(v); else C[idx] = v;
    }
  }
}

// ---- encoder (8 indep blocks, no cross-block sync) + fused X0 GEMM (s>=1 rows) ----
struct EncSmem { uint4 wtail4[16][512]; unsigned hbuf[128]; float gl[1024]; };
struct GemSmem { b16_t As[64][264]; };

__global__ __launch_bounds__(512, 2) void k_enc_x0(
    const unsigned* __restrict__ Whf, const float* __restrict__ encX,
    b16_t* __restrict__ droph,
    const b16_t* __restrict__ seg_bf, const b16_t* __restrict__ l0Wi_bf,
    const float* __restrict__ l0b, float* __restrict__ X0) {
  __shared__ union { EncSmem e; GemSmem g; } sm;
  int tid = threadIdx.x;
  if (blockIdx.x < 8) {
    int batch = blockIdx.x;
    int r0 = tid, r1 = tid + 512;               // rows of Wh: gate = r>>8, dim = r&255
    unsigned wa[96], wb[96];
    {
      const uint4* p0 = (const uint4*)(Whf + (size_t)r0 * 128);
      const uint4* p1 = (const uint4*)(Whf + (size_t)r1 * 128);
#pragma unroll
      for (int i = 0; i < 24; ++i) {
        uint4 v = p0[i];
        wa[4*i] = v.x; wa[4*i+1] = v.y; wa[4*i+2] = v.z; wa[4*i+3] = v.w;
      }
#pragma unroll
      for (int i = 0; i < 24; ++i) {
        uint4 v = p1[i];
        wb[4*i] = v.x; wb[4*i+1] = v.y; wb[4*i+2] = v.z; wb[4*i+3] = v.w;
      }
#pragma unroll
      for (int i = 0; i < 8; ++i) sm.e.wtail4[i][tid] = p0[24 + i];
#pragma unroll
      for (int i = 0; i < 8; ++i) sm.e.wtail4[8 + i][tid] = p1[24 + i];
    }
    // opaque defs: non-rematerializable -> keep in VGPRs
#pragma unroll
    for (int i = 0; i < 96; ++i) asm volatile("v_mov_b32 %0, %0" : "+v"(wa[i]));
#pragma unroll
    for (int i = 0; i < 96; ++i) asm volatile("v_mov_b32 %0, %0" : "+v"(wb[i]));
    if (tid < 128) sm.e.hbuf[tid] = 0;
    float c = 0.f;
    __syncthreads();
#pragma unroll 1
    for (int t = 0; t < 128; ++t) {
      const float* ex = encX + ((size_t)t * 8 + batch) * 1024;
      float a0 = ex[r0], a1 = ex[r1];
      float s0 = 0.f, s1 = 0.f, s2 = 0.f, s3 = 0.f;
#pragma unroll
      for (int j = 0; j < 24; ++j) {            // h dims 0..191 (VGPR weights)
        uint4 hv = *(const uint4*)&sm.e.hbuf[4 * j];
        s0 = FDOT2(bch(hv.x), bch(wa[4*j+0]), s0);
        s0 = FDOT2(bch(hv.y), bch(wa[4*j+1]), s0);
        s1 = FDOT2(bch(hv.z), bch(wa[4*j+2]), s1);
        s1 = FDOT2(bch(hv.w), bch(wa[4*j+3]), s1);
        s2 = FDOT2(bch(hv.x), bch(wb[4*j+0]), s2);
        s2 = FDOT2(bch(hv.y), bch(wb[4*j+1]), s2);
        s3 = FDOT2(bch(hv.z), bch(wb[4*j+2]), s3);
        s3 = FDOT2(bch(hv.w), bch(wb[4*j+3]), s3);
      }
#pragma unroll
      for (int j = 0; j < 8; ++j) {             // h dims 192..255 (LDS weights)
        uint4 hv = *(const uint4*)&sm.e.hbuf[96 + 4 * j];
        uint4 w0 = sm.e.wtail4[j][tid];
        uint4 w1 = sm.e.wtail4[8 + j][tid];
        s0 = FDOT2(bch(hv.x), bch(w0.x), s0);
        s0 = FDOT2(bch(hv.y), bch(w0.y), s0);
        s1 = FDOT2(bch(hv.z), bch(w0.z), s1);
        s1 = FDOT2(bch(hv.w), bch(w0.w), s1);
        s2 = FDOT2(bch(hv.x), bch(w1.x), s2);
        s2 = FDOT2(bch(hv.y), bch(w1.y), s2);
        s3 = FDOT2(bch(hv.z), bch(w1.z), s3);
        s3 = FDOT2(bch(hv.w), bch(w1.w), s3);
      }
      sm.e.gl[r0] = a0 + s0 + s1;
      sm.e.gl[r1] = a1 + s2 + s3;
      __syncthreads();
      if (tid < 256) {
        float gi = sm.e.gl[tid],       gf = sm.e.gl[256 + tid];
        float gg = sm.e.gl[512 + tid], go = sm.e.gl[768 + tid];
        float c2 = sigm_(gf) * c + sigm_(gi) * tanh_(gg);
        float h2 = sigm_(go) * tanh_(c2);
        c = c2;
        droph[((size_t)t * 8 + batch) * 256 + tid] = f2bf(0.1f * h2);
        ((_Float16*)sm.e.hbuf)[tid] = (_Float16)h2;
      }
      __syncthreads();
    }
  } else {
    // ---- X0 rows with s>=1: 4096 rows; ps(j) = j + j/4 + 1 ----
    int g = blockIdx.x - 8;                     // 0..63
    int j0 = g * 64;
    for (int i = tid; i < 64 * 32; i += 512) {
      int r = i >> 5, cc = (i & 31) * 8;
      int jj = j0 + r, ps = jj + (jj >> 2) + 1;
      *(u16x8*)&sm.g.As[r][cc] = *(const u16x8*)(seg_bf + (size_t)ps * 256 + cc);
    }
    __syncthreads();
    int w = tid >> 6, l = tid & 63, lr = l & 15, kg = l >> 4;
    int mt = w & 3, hn = w >> 2;
    s16x8 af[8];
#pragma unroll
    for (int kk = 0; kk < 8; ++kk)
      af[kk] = *(const s16x8*)&sm.g.As[mt * 16 + lr][kk * 32 + kg * 8];
#pragma unroll 1
    for (int nb = 0; nb < 4; ++nb) {
      int nc0 = hn * 512 + nb * 128;
      f32x4 acc[8];
#pragma unroll
      for (int nt = 0; nt < 8; ++nt) acc[nt] = f32x4{0.f, 0.f, 0.f, 0.f};
#pragma unroll
      for (int nt = 0; nt < 8; ++nt) {
        int n = nc0 + nt * 16 + lr;
        const b16_t* bp = l0Wi_bf + (size_t)n * 256 + kg * 8;
#pragma unroll
        for (int kk = 0; kk < 8; ++kk)
          acc[nt] = __builtin_amdgcn_mfma_f32_16x16x32_bf16(
              af[kk], *(const s16x8*)(bp + kk * 32), acc[nt], 0, 0, 0);
      }
#pragma unroll
      for (int nt = 0; nt < 8; ++nt) {
        int n = nc0 + nt * 16 + lr;
        float ob = l0b[n];
#pragma unroll
        for (int r = 0; r < 4; ++r) {
          int jj = j0 + mt * 16 + kg * 4 + r;
          int ps = jj + (jj >> 2) + 1;
          X0[(size_t)ps * 1024 + n] = acc[nt][r] + ob;
        }
      }
    }
  }
}

// ---------------- fused decoder step: BOTH layers + cells, in-register ----------------
__global__ __launch_bounds__(512) void k_dec2(
    b16_t* __restrict__ hcat,            // [1024][512] : [h0 | h1] bf16
    const b16_t* __restrict__ l0Wh_bf,   // [1024][256]
    const b16_t* __restrict__ Wcat_bf,   // [1024][512]  ([l1Wi | l1Wh])
    const float* __restrict__ X0,        // [5120][1024]
    const float* __restrict__ l1b,
    float* __restrict__ c0, float* __restrict__ c1,
    b16_t* __restrict__ dec_out, int s) {
  __shared__ b16_t A0s[32][264];
  __shared__ b16_t A1s[32][520];
  int tid = threadIdx.x;
  int R0 = blockIdx.x * 32;
  for (int i = tid; i < 32 * 32; i += 512) {
    int r = i >> 5, cc = (i & 31) * 8;
    *(u16x8*)&A0s[r][cc] = *(const u16x8*)(hcat + (size_t)(R0 + r) * 512 + cc);
    *(u16x8*)&A1s[r][256 + cc] = *(const u16x8*)(hcat + (size_t)(R0 + r) * 512 + 256 + cc);
  }
  __syncthreads();
  int w = tid >> 6, l = tid & 63, lr = l & 15, kg = l >> 4;
  int m2 = w & 1, dg = w >> 1;                 // Mtile (16 rows), dim group (64 dims)
  s16x8 af[8];
#pragma unroll
  for (int kk = 0; kk < 8; ++kk)
    af[kk] = *(const s16x8*)&A0s[m2 * 16 + lr][kk * 32 + kg * 8];
#pragma unroll 1
  for (int dt = 0; dt < 4; ++dt) {
    int d = dg * 64 + dt * 16 + lr;
    f32x4 ai{}, afv{}, ag{}, ao{};
#pragma unroll
    for (int kk = 0; kk < 8; ++kk) {
      ai  = __builtin_amdgcn_mfma_f32_16x16x32_bf16(af[kk],
              *(const s16x8*)(l0Wh_bf + (size_t)(d) * 256 + kk * 32 + kg * 8), ai, 0, 0, 0);
      afv = __builtin_amdgcn_mfma_f32_16x16x32_bf16(af[kk],
              *(const s16x8*)(l0Wh_bf + (size_t)(256 + d) * 256 + kk * 32 + kg * 8), afv, 0, 0, 0);
      ag  = __builtin_amdgcn_mfma_f32_16x16x32_bf16(af[kk],
              *(const s16x8*)(l0Wh_bf + (size_t)(512 + d) * 256 + kk * 32 + kg * 8), ag, 0, 0, 0);
      ao  = __builtin_amdgcn_mfma_f32_16x16x32_bf16(af[kk],
              *(const s16x8*)(l0Wh_bf + (size_t)(768 + d) * 256 + kk * 32 + kg * 8), ao, 0, 0, 0);
    }
#pragma unroll
    for (int r = 0; r < 4; ++r) {
      int p = R0 + m2 * 16 + kg * 4 + r;
      const float* xp = X0 + ((size_t)p * 5 + s) * 1024;
      float gi = ai[r] + xp[d],        gf = afv[r] + xp[256 + d];
      float gg = ag[r] + xp[512 + d],  go = ao[r] + xp[768 + d];
      float c = c0[(size_t)p * 256 + d];
      float c2 = sigm_(gf) * c + sigm_(gi) * tanh_(gg);
      float h2 = sigm_(go) * tanh_(c2);
      c0[(size_t)p * 256 + d] = c2;
      b16_t hb = f2bf(h2);
      A1s[m2 * 16 + kg * 4 + r][d] = hb;
      hcat[(size_t)p * 512 + d] = hb;
    }
  }
  __syncthreads();
#pragma unroll 1
  for (int dt = 0; dt < 4; ++dt) {
    int d = dg * 64 + dt * 16 + lr;
    f32x4 ai{}, afv{}, ag{}, ao{};
#pragma unroll
    for (int kk = 0; kk < 16; ++kk) {
      s16x8 a2 = *(const s16x8*)&A1s[m2 * 16 + lr][kk * 32 + kg * 8];
      ai  = __builtin_amdgcn_mfma_f32_16x16x32_bf16(a2,
              *(const s16x8*)(Wcat_bf + (size_t)(d) * 512 + kk * 32 + kg * 8), ai, 0, 0, 0);
      afv = __builtin_amdgcn_mfma_f32_16x16x32_bf16(a2,
              *(const s16x8*)(Wcat_bf + (size_t)(256 + d) * 512 + kk * 32 + kg * 8), afv, 0, 0, 0);
      ag  = __builtin_amdgcn_mfma_f32_16x16x32_bf16(a2,
              *(const s16x8*)(Wcat_bf + (size_t)(512 + d) * 512 + kk * 32 + kg * 8), ag, 0, 0, 0);
      ao  = __builtin_amdgcn_mfma_f32_16x16x32_bf16(a2,
              *(const s16x8*)(Wcat_bf + (size_t)(768 + d) * 512 + kk * 32 + kg * 8), ao, 0, 0, 0);
    }
#pragma unroll
    for (int r = 0; r < 4; ++r) {
      int p = R0 + m2 * 16 + kg * 4 + r;
      float gi = ai[r] + l1b[d],        gf = afv[r] + l1b[256 + d];
      float gg = ag[r] + l1b[512 + d],  go = ao[r] + l1b[768 + d];
      float c = c1[(size_t)p * 256 + d];
      float c2 = sigm_(gf) * c + sigm_(gi) * tanh_(gg);
      float h2 = sigm_(go) * tanh_(c2);
      c1[(size_t)p * 256 + d] = c2;
      b16_t hb = f2bf(h2);
      hcat[(size_t)p * 512 + 256 + d] = hb;
      dec_out[((size_t)p * 5 + s) * 256 + d] = hb;
    }
  }
}

// ---------------- logits + fused sum(exp): M=128 tiles, A-frags in regs ----------------
__global__ __launch_bounds__(512) void k_logits(const b16_t* __restrict__ Abf,
                                                const b16_t* __restrict__ emb_bf,
                                                const float* __restrict__ out_b,
                                                float* __restrict__ sumexp) {
  __shared__ b16_t Bs[64][264];
  int tid = threadIdx.x;
  int rowBase = blockIdx.x * 128;
  int w = tid >> 6, l = tid & 63, lr = l & 15, kg = l >> 4;
  s16x8 af[8];
  {
    const b16_t* arow = Abf + (size_t)(rowBase + w * 16 + lr) * 256;
#pragma unroll
    for (int kk = 0; kk < 8; ++kk) af[kk] = *(const s16x8*)(arow + kk * 32 + kg * 8);
  }
  float runsum[4] = {0.f, 0.f, 0.f, 0.f};
  int t0 = blockIdx.y * 12, t1 = (t0 + 12 < 157) ? (t0 + 12) : 157;
  for (int tile = t0; tile < t1; ++tile) {
    int colBase = tile * 64;
    __syncthreads();
    for (int i = tid; i < 64 * 32; i += 512) {
      int r = i >> 5, cc = (i & 31) * 8;
      int vrow = colBase + r;
      u16x8 bv = {0, 0, 0, 0, 0, 0, 0, 0};
      if (vrow < V_) bv = *(const u16x8*)(emb_bf + (size_t)vrow * D_ + cc);
      *(u16x8*)&Bs[r][cc] = bv;
    }
    __syncthreads();
    f32x4 acc[4] = {{0.f,0.f,0.f,0.f},{0.f,0.f,0.f,0.f},{0.f,0.f,0.f,0.f},{0.f,0.f,0.f,0.f}};
#pragma unroll
    for (int kk = 0; kk < 8; ++kk) {
#pragma unroll
      for (int f = 0; f < 4; ++f) {
        s16x8 b = *(const s16x8*)&Bs[f * 16 + lr][kk * 32 + kg * 8];
        acc[f] = __builtin_amdgcn_mfma_f32_16x16x32_bf16(af[kk], b, acc[f], 0, 0, 0);
      }
    }
#pragma unroll
    for (int f = 0; f < 4; ++f) {
      int n = colBase + f * 16 + lr;
      if (n < V_) {
        float ob = out_b[n];
#pragma unroll
        for (int r = 0; r < 4; ++r) runsum[r] += __expf(acc[f][r] + ob);
      }
    }
  }
#pragma unroll
  for (int r = 0; r < 4; ++r) {
    float rs = runsum[r];
    rs += __shfl_xor(rs, 1, 64);
    rs += __shfl_xor(rs, 2, 64);
    rs += __shfl_xor(rs, 4, 64);
    rs += __shfl_xor(rs, 8, 64);
    if (lr == 0) atomicAdd(&sumexp[rowBase + w * 16 + kg * 4 + r], rs);
  }
}

// ---------------- target / EOS logit extraction ----------------
__global__ void k_extract(const b16_t* __restrict__ dec_h, const b16_t* __restrict__ emb_bf,
                          const float* __restrict__ out_b, const int* __restrict__ x_ids,
                          float* __restrict__ tl, float* __restrict__ el) {
  int p = blockIdx.x, lane = threadIdx.x;       // 64 threads
  int t = p >> 3, b = p & 7;
  for (int s = 0; s < S_; ++s) {
    const b16_t* hr = dec_h + ((size_t)p * S_ + s) * D_;
    float hv[4];
#pragma unroll
    for (int j = 0; j < 4; ++j) hv[j] = bf2f(hr[lane * 4 + j]);
    if (s < MS_) {
      int pos = t + s; if (pos > T_ - 1) pos = T_ - 1;
      int tok = x_ids[b * (T_ + 2) + pos + 1];
      const b16_t* er = emb_bf + (size_t)tok * D_;
      float ps = 0.f;
#pragma unroll
      for (int j = 0; j < 4; ++j) ps += hv[j] * bf2f(er[lane * 4 + j]);
      for (int m = 1; m < 64; m <<= 1) ps += __shfl_xor(ps, m, 64);
      if (lane == 0) tl[p * MS_ + s] = ps + out_b[tok];
    }
    if (s >= 1) {
      const b16_t* er = emb_bf + (size_t)EOS_ * D_;
      float ps = 0.f;
#pragma unroll
      for (int j = 0; j < 4; ++j) ps += hv[j] * bf2f(er[lane * 4 + j]);
      for (int m = 1; m < 64; m <<= 1) ps += __shfl_xor(ps, m, 64);
      if (lane == 0) el[p * MS_ + (s - 1)] = ps + out_b[EOS_];
    }
  }
}

// ---------------- final: log-probs, DP, loss ----------------
__global__ __launch_bounds__(256) void k_final(const float* __restrict__ sumexp,
                                               const float* __restrict__ tl,
                                               const float* __restrict__ el,
                                               const int* __restrict__ lens,
                                               float* __restrict__ out) {
  __shared__ float logpy[T_][S_][B_];
  __shared__ float alpha[T_ + 1][B_];
  int tid = threadIdx.x;
  for (int p = tid; p < T_ * B_; p += 256) {
    int t = p >> 3, b = p & 7;
    float lz[S_];
#pragma unroll
    for (int s = 0; s < S_; ++s) lz[s] = __logf(sumexp[p * S_ + s]);
    float cum = 0.f, cums[MS_];
#pragma unroll
    for (int s = 0; s < MS_; ++s) {
      float tlp = tl[p * MS_ + s] - lz[s];
      if (t + s < T_) cum += tlp;
      cums[s] = cum;
    }
#pragma unroll
    for (int k = 1; k <= MS_; ++k) {
      float bv = -1000000.0f;
      if (t + k <= T_) bv = cums[k - 1] + (el[p * MS_ + (k - 1)] - lz[k]);
      logpy[t][k][b] = bv;
    }
  }
  __syncthreads();
  if (tid < B_) {
    int b = tid;
    alpha[0][b] = 0.f;
    for (int j = 1; j <= T_; ++j) {
      float vs[MS_], vmax = -1e30f;
#pragma unroll
      for (int k = 1; k <= MS_; ++k) {
        float vv = -2000000.0f;
        if (j - k >= 0) vv = alpha[j - k][b] + logpy[j - k][k][b];
        vs[k - 1] = vv;
        if (vv > vmax) vmax = vv;
      }
      float ssum = 0.f;
#pragma unroll
      for (int k = 0; k < MS_; ++k) ssum += __expf(vs[k] - vmax);
      alpha[j][b] = vmax + __logf(ssum);
    }
  }
  __syncthreads();
  if (tid == 0) {
    float num = 0.f, den = 0.f;
    for (int b = 0; b < B_; ++b) { num += alpha[lens[b]][b]; den += (float)lens[b]; }
    out[0] = -num / den;
  }
}

// ---------------- host ----------------
extern "C" void kernel_launch(void* const* d_in, const int* in_sizes, int n_in,
                              void* d_out, int out_size, void* d_ws, size_t ws_size,
                              hipStream_t stream) {
  const int* x_ids   = (const int*)d_in[0];
  const int* lens    = (const int*)d_in[1];
  const float* emb   = (const float*)d_in[2];
  const float* y_st  = (const float*)d_in[3];
  const float* cWi   = (const float*)d_in[4];
  const float* cWh   = (const float*)d_in[5];
  const float* cb    = (const float*)d_in[6];
  const float* y0W   = (const float*)d_in[7];
  const float* y0b   = (const float*)d_in[8];
  const float* hlW   = (const float*)d_in[9];
  const float* hlb   = (const float*)d_in[10];
  const float* l0Wi  = (const float*)d_in[11];
  const float* l0Wh  = (const float*)d_in[12];
  const float* l0b   = (const float*)d_in[13];
  const float* l1Wi  = (const float*)d_in[14];
  const float* l1Wh  = (const float*)d_in[15];
  const float* l1b   = (const float*)d_in[16];
  const float* outb  = (const float*)d_in[17];
  float* out = (float*)d_out;
  (void)in_sizes; (void)n_in; (void)out_size; (void)ws_size;

  char* ws = (char*)d_ws;
  size_t cur = 0;
  auto alloc = [&](size_t bytes) { size_t o = cur; cur += (bytes + 255) & ~(size_t)255; return o; };
  b16_t* emb_bf    = (b16_t*)(ws + alloc((size_t)V_ * D_ * 2));
  b16_t* cWi_bf    = (b16_t*)(ws + alloc(1024 * 256 * 2));
  b16_t* y0W_bf    = (b16_t*)(ws + alloc(256 * 256 * 2));
  b16_t* hlW_bf    = (b16_t*)(ws + alloc(512 * 256 * 2));
  b16_t* l0Wi_bf   = (b16_t*)(ws + alloc(1024 * 256 * 2));
  b16_t* l0Wh_bf   = (b16_t*)(ws + alloc(1024 * 256 * 2));
  b16_t* Wcat_bf   = (b16_t*)(ws + alloc(1024 * 512 * 2));
  unsigned* Whf    = (unsigned*)(ws + alloc(1024 * 128 * 4));
  b16_t* seq_bf    = (b16_t*)(ws + alloc(1024 * 256 * 2));
  float* encX      = (float*)(ws + alloc((size_t)1024 * 1024 * 4));
  b16_t* droph_bf  = (b16_t*)(ws + alloc(1024 * 256 * 2));
  b16_t* hcat      = (b16_t*)(ws + alloc(1024 * 512 * 2));
  b16_t* seg_bf    = (b16_t*)(ws + alloc((size_t)5120 * 256 * 2));
  float* X0        = (float*)(ws + alloc((size_t)5120 * 1024 * 4));
  float* c0        = (float*)(ws + alloc((size_t)2 * 1024 * 256 * 4));
  float* c1        = c0 + 1024 * 256;
  b16_t* dec_h_bf  = (b16_t*)(ws + alloc((size_t)5120 * 256 * 2));
  float* sumexp    = (float*)(ws + alloc(5120 * 4));
  float* tl        = (float*)(ws + alloc(1024 * MS_ * 4));
  float* el        = (float*)(ws + alloc(1024 * MS_ * 4));

  hipMemsetAsync(sumexp, 0, 5120 * 4, stream);
  hipMemsetAsync(c0, 0, (size_t)2 * 1024 * 256 * 4, stream);

  k_prep<<<1024, 256, 0, stream>>>(emb, cWi, y0W, hlW, l0Wi, l0Wh, l1Wi, l1Wh, cWh,
                                   x_ids, y_st,
                                   emb_bf, cWi_bf, y0W_bf, hlW_bf, l0Wi_bf, l0Wh_bf,
                                   Wcat_bf, Whf, seq_bf, seg_bf);

  // encX = seq @ cWi^T + cb  (M=1024, N=1024)
  k_gemm<<<dim3(16, 16), 256, 0, stream>>>(seq_bf, 256, cWi_bf, cb, encX, 1024, 0, 0);
  // encoder (blocks 0..7) + X0 rows s>=1 (blocks 8..71)
  k_enc_x0<<<72, 512, 0, stream>>>(Whf, encX, droph_bf, seg_bf, l0Wi_bf, l0b, X0);

  // y_in0 -> seg rows s=0 (bf16, row stride 1280)
  k_gemm<<<dim3(16, 4), 256, 0, stream>>>(droph_bf, 256, y0W_bf, y0b,
                                          (float*)seg_bf, 1280, 0, 1);
  // hlin -> hcat (tanh, bf16, row stride 512)
  k_gemm<<<dim3(16, 8), 256, 0, stream>>>(droph_bf, 256, hlW_bf, hlb,
                                          (float*)hcat, 512, 1, 1);
  // X0 rows s=0: A = seg rows p*5 (lda=1280), C rows p*5 (ldc=5120)
  k_gemm<<<dim3(16, 16), 256, 0, stream>>>(seg_bf, 1280, l0Wi_bf, l0b, X0, 5120, 0, 0);

  for (int s = 0; s < S_; ++s)
    k_dec2<<<32, 512, 0, stream>>>(hcat, l0Wh_bf, Wcat_bf, X0, l1b, c0, c1, dec_h_bf, s);

  k_logits<<<dim3(40, 14), 512, 0, stream>>>(dec_h_bf, emb_bf, outb, sumexp);
  k_extract<<<1024, 64, 0, stream>>>(dec_h_bf, emb_bf, outb, x_ids, tl, el);
  k_final<<<1, 256, 0, stream>>>(sumexp, tl, el, lens, out);
}

// Round 5
// 657.260 us; speedup vs baseline: 1.3660x; 1.3660x over previous
//
#include <hip/hip_runtime.h>

#define V_ 10000
#define D_ 256
#define T_ 128
#define B_ 8
#define MS_ 4
#define S_ 5
#define EOS_ 4

typedef unsigned short b16_t;
typedef __attribute__((ext_vector_type(8))) short s16x8;
typedef __attribute__((ext_vector_type(8))) unsigned short u16x8;
typedef __attribute__((ext_vector_type(4))) float f32x4;
typedef __attribute__((ext_vector_type(2))) _Float16 h16x2;

__device__ inline b16_t f2bf(float f) {
  union { float f; unsigned u; } v; v.f = f;
  unsigned r = v.u + 0x7FFFu + ((v.u >> 16) & 1u);
  return (b16_t)(r >> 16);
}
__device__ inline float bf2f(b16_t h) {
  union { unsigned u; float f; } v; v.u = ((unsigned)h) << 16; return v.f;
}
__device__ inline float sigm_(float x) { return 1.0f / (1.0f + __expf(-x)); }
__device__ inline float tanh_(float x) { return 2.0f / (1.0f + __expf(-2.0f * x)) - 1.0f; }
__device__ inline h16x2 bch(unsigned u) { return __builtin_bit_cast(h16x2, u); }
__device__ inline unsigned pkh(float a, float b) {
  h16x2 v; v.x = (_Float16)a; v.y = (_Float16)b;
  return __builtin_bit_cast(unsigned, v);
}

#if __has_builtin(__builtin_amdgcn_fdot2)
#define FDOT2(a, b, c) __builtin_amdgcn_fdot2((a), (b), (c), false)
#else
#define FDOT2(a, b, c) ((c) + (float)(a).x * (float)(b).x + (float)(a).y * (float)(b).y)
#endif

// ---------------- prep: weight casts + seq + seg(s>=1) ----------------
__device__ inline void cvt4(const float* __restrict__ s, b16_t* __restrict__ d) {
  float4 v = *(const float4*)s;
  ushort4 o = { f2bf(v.x), f2bf(v.y), f2bf(v.z), f2bf(v.w) };
  *(ushort4*)d = o;
}

__global__ void k_prep(const float* __restrict__ emb, const float* __restrict__ cWi,
                       const float* __restrict__ y0W, const float* __restrict__ hlW,
                       const float* __restrict__ l0Wi, const float* __restrict__ l0Wh,
                       const float* __restrict__ l1Wi, const float* __restrict__ l1Wh,
                       const float* __restrict__ cWh, const int* __restrict__ x_ids,
                       const float* __restrict__ y_st,
                       b16_t* __restrict__ emb_bf, b16_t* __restrict__ cWi_bf,
                       b16_t* __restrict__ y0W_bf, b16_t* __restrict__ hlW_bf,
                       b16_t* __restrict__ l0Wi_bf, b16_t* __restrict__ l0Wh_bf,
                       b16_t* __restrict__ Wcat_bf, unsigned* __restrict__ Whf,
                       b16_t* __restrict__ seq_bf, b16_t* __restrict__ seg_bf) {
  for (long i = (long)blockIdx.x * blockDim.x + threadIdx.x; i < 1410048L;
       i += (long)gridDim.x * blockDim.x) {
    if (i < 640000L) { cvt4(emb + i * 4, emb_bf + i * 4); }
    else if (i < 705536L) { long j = i - 640000L; cvt4(cWi + j * 4, cWi_bf + j * 4); }
    else if (i < 721920L) { long j = i - 705536L; cvt4(y0W + j * 4, y0W_bf + j * 4); }
    else if (i < 754688L) { long j = i - 721920L; cvt4(hlW + j * 4, hlW_bf + j * 4); }
    else if (i < 820224L) { long j = i - 754688L; cvt4(l0Wi + j * 4, l0Wi_bf + j * 4); }
    else if (i < 885760L) { long j = i - 820224L; cvt4(l0Wh + j * 4, l0Wh_bf + j * 4); }
    else if (i < 1016832L) {
      long j = (i - 885760L) * 4;
      long n = j >> 9; int k = (int)(j & 511);
      const float* src = (k < 256) ? (l1Wi + n * 256 + k) : (l1Wh + n * 256 + (k - 256));
      cvt4(src, Wcat_bf + j);
    } else if (i < 1082368L) {
      long j = i - 1016832L;
      float4 v = *(const float4*)(cWh + j * 4);
      Whf[2 * j] = pkh(v.x, v.y);
      Whf[2 * j + 1] = pkh(v.z, v.w);
    } else if (i < 1147904L) {
      long j = i - 1082368L;                    // seq_bf: [1024][256]
      int m = (int)(j >> 6), c = (int)(j & 63) * 4;
      int t = m >> 3, b = m & 7;
      const float* src = (t == 0) ? (y_st + c)
                                  : (emb + (size_t)x_ids[b * (T_ + 2) + t] * D_ + c);
      cvt4(src, seq_bf + (size_t)m * D_ + c);
    } else {
      long j = i - 1147904L;                    // seg rows s>=1: 4096 rows x 64 chunks
      int r = (int)(j >> 6), c = (int)(j & 63) * 4;
      int p = r >> 2, s = 1 + (r & 3);
      int t = p >> 3, b = p & 7;
      int tt = t + s - 1;
      int ps = r + (r >> 2) + 1;                // = p*5 + s
      if (tt < T_) {
        int tok = x_ids[b * (T_ + 2) + tt + 1];
        cvt4(emb + (size_t)tok * D_ + c, seg_bf + (size_t)ps * 256 + c);
      } else {
        ushort4 z = {0, 0, 0, 0};
        *(ushort4*)(seg_bf + (size_t)ps * 256 + c) = z;
      }
    }
  }
}

// ---- big GEMM launch: encX (blocks x<16) + X0 rows s>=1 (blocks x>=16) ----
__global__ __launch_bounds__(256) void k_gemm_big(
    const b16_t* __restrict__ seq_bf, const b16_t* __restrict__ cWi_bf,
    const float* __restrict__ cb, float* __restrict__ encX,
    const b16_t* __restrict__ seg_bf, const b16_t* __restrict__ l0Wi_bf,
    const float* __restrict__ l0b, float* __restrict__ X0) {
  __shared__ b16_t As[64][264];
  __shared__ b16_t Bs[64][264];
  int bx = blockIdx.x, by = blockIdx.y;
  const b16_t* Ab; const b16_t* Bw; const float* bias; float* C;
  int rb, remap;
  if (bx < 16) { Ab = seq_bf; Bw = cWi_bf; bias = cb; C = encX; rb = bx * 64; remap = 0; }
  else { Ab = seg_bf; Bw = l0Wi_bf; bias = l0b; C = X0; rb = (bx - 16) * 64; remap = 1; }
  int colBase = by * 64;
  int tid = threadIdx.x;
  for (int i = tid; i < 64 * 32; i += 256) {
    int r = i >> 5, c = (i & 31) * 8;
    int rr = rb + r;
    int ar = remap ? (rr + (rr >> 2) + 1) : rr;
    *(u16x8*)&As[r][c] = *(const u16x8*)(Ab + (size_t)ar * 256 + c);
    *(u16x8*)&Bs[r][c] = *(const u16x8*)(Bw + (size_t)(colBase + r) * 256 + c);
  }
  __syncthreads();
  int w = tid >> 6, l = tid & 63, lr = l & 15, kg = l >> 4;
  f32x4 acc[4] = {{0.f,0.f,0.f,0.f},{0.f,0.f,0.f,0.f},{0.f,0.f,0.f,0.f},{0.f,0.f,0.f,0.f}};
  for (int kk = 0; kk < 8; ++kk) {
    s16x8 a = *(const s16x8*)&As[w * 16 + lr][kk * 32 + kg * 8];
#pragma unroll
    for (int f = 0; f < 4; ++f) {
      s16x8 b = *(const s16x8*)&Bs[f * 16 + lr][kk * 32 + kg * 8];
      acc[f] = __builtin_amdgcn_mfma_f32_16x16x32_bf16(a, b, acc[f], 0, 0, 0);
    }
  }
#pragma unroll
  for (int f = 0; f < 4; ++f) {
#pragma unroll
    for (int r = 0; r < 4; ++r) {
      int mm = rb + w * 16 + kg * 4 + r;
      int cr = remap ? (mm + (mm >> 2) + 1) : mm;
      int n = colBase + f * 16 + lr;
      C[(size_t)cr * 1024 + n] = acc[f][r] + bias[n];
    }
  }
}

// ---------------- encoder: 8 blocks, pure VALU, weights VGPR+LDS resident ----------------
__global__ __launch_bounds__(512) __attribute__((amdgpu_waves_per_eu(2, 2)))
void k_encoder(const unsigned* __restrict__ Whf, const float* __restrict__ encX,
               b16_t* __restrict__ droph) {
  __shared__ uint4 wtail[16][512];     // 128 KB: per-row dims 192..255
  __shared__ unsigned hbuf[128];
  __shared__ float gl[1024];
  int batch = blockIdx.x;
  int tid = threadIdx.x;
  int r0 = tid, r1 = tid + 512;
  unsigned wa[96], wb[96];
  {
    const uint4* p0 = (const uint4*)(Whf + (size_t)r0 * 128);
    const uint4* p1 = (const uint4*)(Whf + (size_t)r1 * 128);
#pragma unroll
    for (int i = 0; i < 24; ++i) {
      uint4 v = p0[i];
      wa[4*i] = v.x; wa[4*i+1] = v.y; wa[4*i+2] = v.z; wa[4*i+3] = v.w;
    }
#pragma unroll
    for (int i = 0; i < 24; ++i) {
      uint4 v = p1[i];
      wb[4*i] = v.x; wb[4*i+1] = v.y; wb[4*i+2] = v.z; wb[4*i+3] = v.w;
    }
#pragma unroll
    for (int i = 0; i < 8; ++i) wtail[i][tid] = p0[24 + i];
#pragma unroll
    for (int i = 0; i < 8; ++i) wtail[8 + i][tid] = p1[24 + i];
  }
#pragma unroll
  for (int i = 0; i < 96; ++i) asm volatile("v_mov_b32 %0, %0" : "+v"(wa[i]));
#pragma unroll
  for (int i = 0; i < 96; ++i) asm volatile("v_mov_b32 %0, %0" : "+v"(wb[i]));
  if (tid < 128) hbuf[tid] = 0;
  float c = 0.f;
  float a0n = encX[((size_t)0 * 8 + batch) * 1024 + r0];
  float a1n = encX[((size_t)0 * 8 + batch) * 1024 + r1];
  __syncthreads();
#pragma unroll 1
  for (int t = 0; t < 128; ++t) {
    float a0 = a0n, a1 = a1n;
    if (t < 127) {
      a0n = encX[((size_t)(t + 1) * 8 + batch) * 1024 + r0];
      a1n = encX[((size_t)(t + 1) * 8 + batch) * 1024 + r1];
    }
    float s0 = 0.f, s1 = 0.f, s2 = 0.f, s3 = 0.f;
#pragma unroll
    for (int j = 0; j < 24; ++j) {              // h dims 0..191 (VGPR weights)
      uint4 hv = *(const uint4*)&hbuf[4 * j];
      s0 = FDOT2(bch(hv.x), bch(wa[4*j+0]), s0);
      s0 = FDOT2(bch(hv.y), bch(wa[4*j+1]), s0);
      s1 = FDOT2(bch(hv.z), bch(wa[4*j+2]), s1);
      s1 = FDOT2(bch(hv.w), bch(wa[4*j+3]), s1);
      s2 = FDOT2(bch(hv.x), bch(wb[4*j+0]), s2);
      s2 = FDOT2(bch(hv.y), bch(wb[4*j+1]), s2);
      s3 = FDOT2(bch(hv.z), bch(wb[4*j+2]), s3);
      s3 = FDOT2(bch(hv.w), bch(wb[4*j+3]), s3);
    }
#pragma unroll
    for (int j = 0; j < 8; ++j) {               // h dims 192..255 (LDS weights)
      uint4 hv = *(const uint4*)&hbuf[96 + 4 * j];
      uint4 w0 = wtail[j][tid];
      uint4 w1 = wtail[8 + j][tid];
      s0 = FDOT2(bch(hv.x), bch(w0.x), s0);
      s0 = FDOT2(bch(hv.y), bch(w0.y), s0);
      s1 = FDOT2(bch(hv.z), bch(w0.z), s1);
      s1 = FDOT2(bch(hv.w), bch(w0.w), s1);
      s2 = FDOT2(bch(hv.x), bch(w1.x), s2);
      s2 = FDOT2(bch(hv.y), bch(w1.y), s2);
      s3 = FDOT2(bch(hv.z), bch(w1.z), s3);
      s3 = FDOT2(bch(hv.w), bch(w1.w), s3);
    }
    gl[r0] = a0 + s0 + s1;
    gl[r1] = a1 + s2 + s3;
    __syncthreads();
    if (tid < 256) {
      float gi = gl[tid],       gf = gl[256 + tid];
      float gg = gl[512 + tid], go = gl[768 + tid];
      float c2 = sigm_(gf) * c + sigm_(gi) * tanh_(gg);
      float h2 = sigm_(go) * tanh_(c2);
      c = c2;
      droph[((size_t)t * 8 + batch) * 256 + tid] = f2bf(0.1f * h2);
      ((_Float16*)hbuf)[tid] = (_Float16)h2;
    }
    __syncthreads();
  }
}

// ---------------- fused projections: y_in0 -> seg(s=0), hlin -> hcat ----------------
__global__ __launch_bounds__(256) void k_proj(
    const b16_t* __restrict__ droph, const b16_t* __restrict__ y0W_bf,
    const float* __restrict__ y0b, const b16_t* __restrict__ hlW_bf,
    const float* __restrict__ hlb, b16_t* __restrict__ seg_bf,
    b16_t* __restrict__ hcat) {
  __shared__ b16_t As[64][264];
  __shared__ b16_t Bs[64][264];
  int bx = blockIdx.x, by = blockIdx.y;
  const b16_t* Bw; const float* bias; int colBase, mode;
  if (by < 4) { Bw = y0W_bf; bias = y0b; colBase = by * 64; mode = 0; }
  else { Bw = hlW_bf; bias = hlb; colBase = (by - 4) * 64; mode = 1; }
  int rowBase = bx * 64;
  int tid = threadIdx.x;
  for (int i = tid; i < 64 * 32; i += 256) {
    int r = i >> 5, c = (i & 31) * 8;
    *(u16x8*)&As[r][c] = *(const u16x8*)(droph + (size_t)(rowBase + r) * 256 + c);
    *(u16x8*)&Bs[r][c] = *(const u16x8*)(Bw + (size_t)(colBase + r) * 256 + c);
  }
  __syncthreads();
  int w = tid >> 6, l = tid & 63, lr = l & 15, kg = l >> 4;
  f32x4 acc[4] = {{0.f,0.f,0.f,0.f},{0.f,0.f,0.f,0.f},{0.f,0.f,0.f,0.f},{0.f,0.f,0.f,0.f}};
  for (int kk = 0; kk < 8; ++kk) {
    s16x8 a = *(const s16x8*)&As[w * 16 + lr][kk * 32 + kg * 8];
#pragma unroll
    for (int f = 0; f < 4; ++f) {
      s16x8 b = *(const s16x8*)&Bs[f * 16 + lr][kk * 32 + kg * 8];
      acc[f] = __builtin_amdgcn_mfma_f32_16x16x32_bf16(a, b, acc[f], 0, 0, 0);
    }
  }
#pragma unroll
  for (int f = 0; f < 4; ++f) {
#pragma unroll
    for (int r = 0; r < 4; ++r) {
      int m = rowBase + w * 16 + kg * 4 + r;
      int n = colBase + f * 16 + lr;
      float v = acc[f][r] + bias[n];
      if (mode == 0) seg_bf[(size_t)m * 1280 + n] = f2bf(v);
      else hcat[(size_t)m * 512 + n] = f2bf(tanh_(v));
    }
  }
}

// ------- generic bf16 MFMA GEMM (K=256), used for X0 s=0 rows -------
__global__ __launch_bounds__(256) void k_gemm(const b16_t* __restrict__ A, int lda,
                                              const b16_t* __restrict__ Bw,
                                              const float* __restrict__ bias,
                                              float* __restrict__ C, int ldc) {
  __shared__ b16_t As[64][264];
  __shared__ b16_t Bs[64][264];
  int tid = threadIdx.x;
  int rowBase = blockIdx.x * 64, colBase = blockIdx.y * 64;
  for (int i = tid; i < 64 * 32; i += 256) {
    int r = i >> 5, c = (i & 31) * 8;
    *(u16x8*)&As[r][c] = *(const u16x8*)(A + (size_t)(rowBase + r) * lda + c);
    *(u16x8*)&Bs[r][c] = *(const u16x8*)(Bw + (size_t)(colBase + r) * 256 + c);
  }
  __syncthreads();
  int w = tid >> 6, l = tid & 63, lr = l & 15, kg = l >> 4;
  f32x4 acc[4] = {{0.f,0.f,0.f,0.f},{0.f,0.f,0.f,0.f},{0.f,0.f,0.f,0.f},{0.f,0.f,0.f,0.f}};
  for (int kk = 0; kk < 8; ++kk) {
    s16x8 a = *(const s16x8*)&As[w * 16 + lr][kk * 32 + kg * 8];
#pragma unroll
    for (int f = 0; f < 4; ++f) {
      s16x8 b = *(const s16x8*)&Bs[f * 16 + lr][kk * 32 + kg * 8];
      acc[f] = __builtin_amdgcn_mfma_f32_16x16x32_bf16(a, b, acc[f], 0, 0, 0);
    }
  }
#pragma unroll
  for (int f = 0; f < 4; ++f) {
#pragma unroll
    for (int r = 0; r < 4; ++r) {
      int m = rowBase + w * 16 + kg * 4 + r;
      int n = colBase + f * 16 + lr;
      C[(size_t)m * ldc + n] = acc[f][r] + bias[n];
    }
  }
}

// ---------------- fused decoder step: both layers + cells, 64 blocks ----------------
__global__ __launch_bounds__(512) void k_dec2(
    b16_t* __restrict__ hcat,            // [1024][512] : [h0 | h1] bf16
    const b16_t* __restrict__ l0Wh_bf,   // [1024][256]
    const b16_t* __restrict__ Wcat_bf,   // [1024][512]  ([l1Wi | l1Wh])
    const float* __restrict__ X0,        // [5120][1024]
    const float* __restrict__ l1b,
    float* __restrict__ c0, float* __restrict__ c1,
    b16_t* __restrict__ dec_out, int s) {
  __shared__ b16_t A0s[16][264];
  __shared__ b16_t A1s[16][520];
  int tid = threadIdx.x;
  int R0 = blockIdx.x * 16;
  for (int i = tid; i < 16 * 32; i += 512) {
    int r = i >> 5, cc = (i & 31) * 8;
    *(u16x8*)&A0s[r][cc] = *(const u16x8*)(hcat + (size_t)(R0 + r) * 512 + cc);
    *(u16x8*)&A1s[r][256 + cc] = *(const u16x8*)(hcat + (size_t)(R0 + r) * 512 + 256 + cc);
  }
  __syncthreads();
  int w = tid >> 6, l = tid & 63, lr = l & 15, kg = l >> 4;
  // layer 0: wave w owns dims d in [w*32, w*32+32) across all 4 gates
  {
    s16x8 af[8];
#pragma unroll
    for (int kk = 0; kk < 8; ++kk)
      af[kk] = *(const s16x8*)&A0s[lr][kk * 32 + kg * 8];
    f32x4 acc[4][2];
#pragma unroll
    for (int g = 0; g < 4; ++g)
#pragma unroll
      for (int ct = 0; ct < 2; ++ct) acc[g][ct] = f32x4{0.f, 0.f, 0.f, 0.f};
#pragma unroll
    for (int g = 0; g < 4; ++g)
#pragma unroll
      for (int ct = 0; ct < 2; ++ct) {
        int n = g * 256 + w * 32 + ct * 16 + lr;
        const b16_t* bp = l0Wh_bf + (size_t)n * 256 + kg * 8;
#pragma unroll
        for (int kk = 0; kk < 8; ++kk)
          acc[g][ct] = __builtin_amdgcn_mfma_f32_16x16x32_bf16(
              af[kk], *(const s16x8*)(bp + kk * 32), acc[g][ct], 0, 0, 0);
      }
#pragma unroll
    for (int ct = 0; ct < 2; ++ct)
#pragma unroll
      for (int r = 0; r < 4; ++r) {
        int row = kg * 4 + r, p = R0 + row, d = w * 32 + ct * 16 + lr;
        const float* xp = X0 + ((size_t)p * 5 + s) * 1024;
        float gi = acc[0][ct][r] + xp[d],       gf = acc[1][ct][r] + xp[256 + d];
        float gg = acc[2][ct][r] + xp[512 + d], go = acc[3][ct][r] + xp[768 + d];
        float cc0 = c0[(size_t)p * 256 + d];
        float c2 = sigm_(gf) * cc0 + sigm_(gi) * tanh_(gg);
        float h2 = sigm_(go) * tanh_(c2);
        c0[(size_t)p * 256 + d] = c2;
        b16_t hb = f2bf(h2);
        A1s[row][d] = hb;
        hcat[(size_t)p * 512 + d] = hb;
      }
  }
  __syncthreads();
  // layer 1: K=512 ([h0_new | h1_prev])
  {
    s16x8 a1[16];
#pragma unroll
    for (int kk = 0; kk < 16; ++kk)
      a1[kk] = *(const s16x8*)&A1s[lr][kk * 32 + kg * 8];
    f32x4 acc[4][2];
#pragma unroll
    for (int g = 0; g < 4; ++g)
#pragma unroll
      for (int ct = 0; ct < 2; ++ct) acc[g][ct] = f32x4{0.f, 0.f, 0.f, 0.f};
#pragma unroll
    for (int g = 0; g < 4; ++g)
#pragma unroll
      for (int ct = 0; ct < 2; ++ct) {
        int n = g * 256 + w * 32 + ct * 16 + lr;
        const b16_t* bp = Wcat_bf + (size_t)n * 512 + kg * 8;
#pragma unroll
        for (int kk = 0; kk < 16; ++kk)
          acc[g][ct] = __builtin_amdgcn_mfma_f32_16x16x32_bf16(
              a1[kk], *(const s16x8*)(bp + kk * 32), acc[g][ct], 0, 0, 0);
      }
#pragma unroll
    for (int ct = 0; ct < 2; ++ct)
#pragma unroll
      for (int r = 0; r < 4; ++r) {
        int row = kg * 4 + r, p = R0 + row, d = w * 32 + ct * 16 + lr;
        float gi = acc[0][ct][r] + l1b[d],       gf = acc[1][ct][r] + l1b[256 + d];
        float gg = acc[2][ct][r] + l1b[512 + d], go = acc[3][ct][r] + l1b[768 + d];
        float cc1 = c1[(size_t)p * 256 + d];
        float c2 = sigm_(gf) * cc1 + sigm_(gi) * tanh_(gg);
        float h2 = sigm_(go) * tanh_(c2);
        c1[(size_t)p * 256 + d] = c2;
        b16_t hb = f2bf(h2);
        hcat[(size_t)p * 512 + 256 + d] = hb;
        dec_out[((size_t)p * 5 + s) * 256 + d] = hb;
      }
  }
}

// ---------------- logits + fused sum(exp): M=128 tiles, A-frags in regs ----------------
__global__ __launch_bounds__(512) void k_logits(const b16_t* __restrict__ Abf,
                                                const b16_t* __restrict__ emb_bf,
                                                const float* __restrict__ out_b,
                                                float* __restrict__ sumexp) {
  __shared__ b16_t Bs[64][264];
  int tid = threadIdx.x;
  int rowBase = blockIdx.x * 128;
  int w = tid >> 6, l = tid & 63, lr = l & 15, kg = l >> 4;
  s16x8 af[8];
  {
    const b16_t* arow = Abf + (size_t)(rowBase + w * 16 + lr) * 256;
#pragma unroll
    for (int kk = 0; kk < 8; ++kk) af[kk] = *(const s16x8*)(arow + kk * 32 + kg * 8);
  }
  float runsum[4] = {0.f, 0.f, 0.f, 0.f};
  int t0 = blockIdx.y * 12, t1 = (t0 + 12 < 157) ? (t0 + 12) : 157;
  for (int tile = t0; tile < t1; ++tile) {
    int colBase = tile * 64;
    __syncthreads();
    for (int i = tid; i < 64 * 32; i += 512) {
      int r = i >> 5, cc = (i & 31) * 8;
      int vrow = colBase + r;
      u16x8 bv = {0, 0, 0, 0, 0, 0, 0, 0};
      if (vrow < V_) bv = *(const u16x8*)(emb_bf + (size_t)vrow * D_ + cc);
      *(u16x8*)&Bs[r][cc] = bv;
    }
    __syncthreads();
    f32x4 acc[4] = {{0.f,0.f,0.f,0.f},{0.f,0.f,0.f,0.f},{0.f,0.f,0.f,0.f},{0.f,0.f,0.f,0.f}};
#pragma unroll
    for (int kk = 0; kk < 8; ++kk) {
#pragma unroll
      for (int f = 0; f < 4; ++f) {
        s16x8 b = *(const s16x8*)&Bs[f * 16 + lr][kk * 32 + kg * 8];
        acc[f] = __builtin_amdgcn_mfma_f32_16x16x32_bf16(af[kk], b, acc[f], 0, 0, 0);
      }
    }
#pragma unroll
    for (int f = 0; f < 4; ++f) {
      int n = colBase + f * 16 + lr;
      if (n < V_) {
        float ob = out_b[n];
#pragma unroll
        for (int r = 0; r < 4; ++r) runsum[r] += __expf(acc[f][r] + ob);
      }
    }
  }
#pragma unroll
  for (int r = 0; r < 4; ++r) {
    float rs = runsum[r];
    rs += __shfl_xor(rs, 1, 64);
    rs += __shfl_xor(rs, 2, 64);
    rs += __shfl_xor(rs, 4, 64);
    rs += __shfl_xor(rs, 8, 64);
    if (lr == 0) atomicAdd(&sumexp[rowBase + w * 16 + kg * 4 + r], rs);
  }
}

// ---------------- target / EOS logit extraction ----------------
__global__ void k_extract(const b16_t* __restrict__ dec_h, const b16_t* __restrict__ emb_bf,
                          const float* __restrict__ out_b, const int* __restrict__ x_ids,
                          float* __restrict__ tl, float* __restrict__ el) {
  int p = blockIdx.x, lane = threadIdx.x;       // 64 threads
  int t = p >> 3, b = p & 7;
  for (int s = 0; s < S_; ++s) {
    const b16_t* hr = dec_h + ((size_t)p * S_ + s) * D_;
    float hv[4];
#pragma unroll
    for (int j = 0; j < 4; ++j) hv[j] = bf2f(hr[lane * 4 + j]);
    if (s < MS_) {
      int pos = t + s; if (pos > T_ - 1) pos = T_ - 1;
      int tok = x_ids[b * (T_ + 2) + pos + 1];
      const b16_t* er = emb_bf + (size_t)tok * D_;
      float ps = 0.f;
#pragma unroll
      for (int j = 0; j < 4; ++j) ps += hv[j] * bf2f(er[lane * 4 + j]);
      for (int m = 1; m < 64; m <<= 1) ps += __shfl_xor(ps, m, 64);
      if (lane == 0) tl[p * MS_ + s] = ps + out_b[tok];
    }
    if (s >= 1) {
      const b16_t* er = emb_bf + (size_t)EOS_ * D_;
      float ps = 0.f;
#pragma unroll
      for (int j = 0; j < 4; ++j) ps += hv[j] * bf2f(er[lane * 4 + j]);
      for (int m = 1; m < 64; m <<= 1) ps += __shfl_xor(ps, m, 64);
      if (lane == 0) el[p * MS_ + (s - 1)] = ps + out_b[EOS_];
    }
  }
}

// ---------------- final: log-probs, DP, loss ----------------
__global__ __launch_bounds__(256) void k_final(const float* __restrict__ sumexp,
                                               const float* __restrict__ tl,
                                               const float* __restrict__ el,
                                               const int* __restrict__ lens,
                                               float* __restrict__ out) {
  __shared__ float logpy[T_][S_][B_];
  __shared__ float alpha[T_ + 1][B_];
  int tid = threadIdx.x;
  for (int p = tid; p < T_ * B_; p += 256) {
    int t = p >> 3, b = p & 7;
    float lz[S_];
#pragma unroll
    for (int s = 0; s < S_; ++s) lz[s] = __logf(sumexp[p * S_ + s]);
    float cum = 0.f, cums[MS_];
#pragma unroll
    for (int s = 0; s < MS_; ++s) {
      float tlp = tl[p * MS_ + s] - lz[s];
      if (t + s < T_) cum += tlp;
      cums[s] = cum;
    }
#pragma unroll
    for (int k = 1; k <= MS_; ++k) {
      float bv = -1000000.0f;
      if (t + k <= T_) bv = cums[k - 1] + (el[p * MS_ + (k - 1)] - lz[k]);
      logpy[t][k][b] = bv;
    }
  }
  __syncthreads();
  if (tid < B_) {
    int b = tid;
    alpha[0][b] = 0.f;
    for (int j = 1; j <= T_; ++j) {
      float vs[MS_], vmax = -1e30f;
#pragma unroll
      for (int k = 1; k <= MS_; ++k) {
        float vv = -2000000.0f;
        if (j - k >= 0) vv = alpha[j - k][b] + logpy[j - k][k][b];
        vs[k - 1] = vv;
        if (vv > vmax) vmax = vv;
      }
      float ssum = 0.f;
#pragma unroll
      for (int k = 0; k < MS_; ++k) ssum += __expf(vs[k] - vmax);
      alpha[j][b] = vmax + __logf(ssum);
    }
  }
  __syncthreads();
  if (tid == 0) {
    float num = 0.f, den = 0.f;
    for (int b = 0; b < B_; ++b) { num += alpha[lens[b]][b]; den += (float)lens[b]; }
    out[0] = -num / den;
  }
}

// ---------------- host ----------------
extern "C" void kernel_launch(void* const* d_in, const int* in_sizes, int n_in,
                              void* d_out, int out_size, void* d_ws, size_t ws_size,
                              hipStream_t stream) {
  const int* x_ids   = (const int*)d_in[0];
  const int* lens    = (const int*)d_in[1];
  const float* emb   = (const float*)d_in[2];
  const float* y_st  = (const float*)d_in[3];
  const float* cWi   = (const float*)d_in[4];
  const float* cWh   = (const float*)d_in[5];
  const float* cb    = (const float*)d_in[6];
  const float* y0W   = (const float*)d_in[7];
  const float* y0b   = (const float*)d_in[8];
  const float* hlW   = (const float*)d_in[9];
  const float* hlb   = (const float*)d_in[10];
  const float* l0Wi  = (const float*)d_in[11];
  const float* l0Wh  = (const float*)d_in[12];
  const float* l0b   = (const float*)d_in[13];
  const float* l1Wi  = (const float*)d_in[14];
  const float* l1Wh  = (const float*)d_in[15];
  const float* l1b   = (const float*)d_in[16];
  const float* outb  = (const float*)d_in[17];
  float* out = (float*)d_out;
  (void)in_sizes; (void)n_in; (void)out_size; (void)ws_size;

  char* ws = (char*)d_ws;
  size_t cur = 0;
  auto alloc = [&](size_t bytes) { size_t o = cur; cur += (bytes + 255) & ~(size_t)255; return o; };
  b16_t* emb_bf    = (b16_t*)(ws + alloc((size_t)V_ * D_ * 2));
  b16_t* cWi_bf    = (b16_t*)(ws + alloc(1024 * 256 * 2));
  b16_t* y0W_bf    = (b16_t*)(ws + alloc(256 * 256 * 2));
  b16_t* hlW_bf    = (b16_t*)(ws + alloc(512 * 256 * 2));
  b16_t* l0Wi_bf   = (b16_t*)(ws + alloc(1024 * 256 * 2));
  b16_t* l0Wh_bf   = (b16_t*)(ws + alloc(1024 * 256 * 2));
  b16_t* Wcat_bf   = (b16_t*)(ws + alloc(1024 * 512 * 2));
  unsigned* Whf    = (unsigned*)(ws + alloc(1024 * 128 * 4));
  b16_t* seq_bf    = (b16_t*)(ws + alloc(1024 * 256 * 2));
  float* encX      = (float*)(ws + alloc((size_t)1024 * 1024 * 4));
  b16_t* droph_bf  = (b16_t*)(ws + alloc(1024 * 256 * 2));
  b16_t* hcat      = (b16_t*)(ws + alloc(1024 * 512 * 2));
  b16_t* seg_bf    = (b16_t*)(ws + alloc((size_t)5120 * 256 * 2));
  float* X0        = (float*)(ws + alloc((size_t)5120 * 1024 * 4));
  float* c0        = (float*)(ws + alloc((size_t)2 * 1024 * 256 * 4));
  float* c1        = c0 + 1024 * 256;
  b16_t* dec_h_bf  = (b16_t*)(ws + alloc((size_t)5120 * 256 * 2));
  float* sumexp    = (float*)(ws + alloc(5120 * 4));
  float* tl        = (float*)(ws + alloc(1024 * MS_ * 4));
  float* el        = (float*)(ws + alloc(1024 * MS_ * 4));

  hipMemsetAsync(sumexp, 0, 5120 * 4, stream);
  hipMemsetAsync(c0, 0, (size_t)2 * 1024 * 256 * 4, stream);

  k_prep<<<1024, 256, 0, stream>>>(emb, cWi, y0W, hlW, l0Wi, l0Wh, l1Wi, l1Wh, cWh,
                                   x_ids, y_st,
                                   emb_bf, cWi_bf, y0W_bf, hlW_bf, l0Wi_bf, l0Wh_bf,
                                   Wcat_bf, Whf, seq_bf, seg_bf);

  // encX (blocks 0..15) + X0 rows s>=1 (blocks 16..79), one launch
  k_gemm_big<<<dim3(80, 16), 256, 0, stream>>>(seq_bf, cWi_bf, cb, encX,
                                               seg_bf, l0Wi_bf, l0b, X0);
  // encoder: 8 blocks, pure VALU
  k_encoder<<<8, 512, 0, stream>>>(Whf, encX, droph_bf);

  // y_in0 -> seg s=0 rows, hlin -> hcat (one launch)
  k_proj<<<dim3(16, 12), 256, 0, stream>>>(droph_bf, y0W_bf, y0b, hlW_bf, hlb,
                                           seg_bf, hcat);
  // X0 rows s=0: A = seg rows p*5 (lda=1280), C rows p*5 (ldc=5120)
  k_gemm<<<dim3(16, 16), 256, 0, stream>>>(seg_bf, 1280, l0Wi_bf, l0b, X0, 5120);

  for (int s = 0; s < S_; ++s)
    k_dec2<<<64, 512, 0, stream>>>(hcat, l0Wh_bf, Wcat_bf, X0, l1b, c0, c1, dec_h_bf, s);

  k_logits<<<dim3(40, 14), 512, 0, stream>>>(dec_h_bf, emb_bf, outb, sumexp);
  k_extract<<<1024, 64, 0, stream>>>(dec_h_bf, emb_bf, outb, x_ids, tl, el);
  k_final<<<1, 256, 0, stream>>>(sumexp, tl, el, lens, out);
}